// Round 1
// baseline (647.787 us; speedup 1.0000x reference)
//
#include <hip/hip_runtime.h>

// MoE forward: shared SwiGLU expert + top-2/8 routed SwiGLU experts + aux loss.
// Strategy: bf16 MFMA (16x16x32) GEMMs, m97-style 128-tile with global_load_lds
// width-16 staging; routed experts via padded per-expert segments (fixed grid,
// graph-capture safe); no atomics on the output path.

typedef unsigned short u16;
typedef unsigned int   u32;
typedef short short8 __attribute__((ext_vector_type(8)));
typedef float f32x4  __attribute__((ext_vector_type(4)));

#define AS1 __attribute__((address_space(1)))
#define AS3 __attribute__((address_space(3)))

constexpr int T  = 8192;
constexpr int H  = 1024;
constexpr int E  = 8;
constexpr int D  = 512;
constexpr int DS = 1024;          // shared expert width
constexpr int PAIR_CAP  = 17408;  // 136 * 128 >= 16384 + 8*127
constexpr int MT_ROUTED = 136;    // routed m-tiles (128 rows each)

__device__ __forceinline__ u16 f2bf(float f){
  u32 u = __builtin_bit_cast(u32, f);
  u += 0x7fffu + ((u >> 16) & 1u);   // round-to-nearest-even
  return (u16)(u >> 16);
}
__device__ __forceinline__ float bf2f(u16 h){
  u32 u = ((u32)h) << 16;
  return __builtin_bit_cast(float, u);
}

// async global->LDS, 16B per lane. LDS dest = wave-uniform base + lane*16.
__device__ __forceinline__ void gl_lds16(const u16* g, u16* l){
  __builtin_amdgcn_global_load_lds((const AS1 void*)g, (AS3 void*)l, 16, 0, 0);
}

// Stage a ROWS x 64(bf16) tile into LDS (row-major, 64-elem row stride).
// Each wave issue covers 8 rows (8 lanes/row * 16B). Optional row gather.
template<int ROWS>
__device__ __forceinline__ void stage_tile(const u16* __restrict__ gbase, int ld, int k0,
                                           int rowbase, const int* __restrict__ gather,
                                           u16* lds, int wave, int lane){
  constexpr int ISS = ROWS / 32;   // issues per wave (4 waves total)
  int lr = lane >> 3, ch = lane & 7;
#pragma unroll
  for (int j = 0; j < ISS; ++j){
    int idx = wave * ISS + j;
    int row = idx * 8 + lr;
    int grow = gather ? gather[rowbase + row] : (rowbase + row);
    const u16* g = gbase + (long)grow * ld + k0 + ch * 8;
    gl_lds16(g, lds + idx * 512);  // 512 u16 = 1024B per issue, wave-uniform
  }
}

// ---------------- router: logits -> softmax -> top2 -> counts + prob sums ----
__global__ void __launch_bounds__(256) router_kernel(
    const float* __restrict__ x, const float* __restrict__ Wr,
    int* __restrict__ topk_idx, float* __restrict__ topk_w,
    int* __restrict__ counts, float* __restrict__ probs_sum)
{
  __shared__ float ps[E];
  int tid = threadIdx.x, lane = tid & 63, wv = tid >> 6;
  if (tid < E) ps[tid] = 0.f;
  __syncthreads();
  int t = blockIdx.x * 4 + wv;
  const float* xr = x + (long)t * H;
  float acc[E];
#pragma unroll
  for (int e = 0; e < E; ++e) acc[e] = 0.f;
  for (int i = 0; i < H / 64; ++i){
    int h = i * 64 + lane;
    float xv = xr[h];
    const float4* wr = (const float4*)(Wr + h * E);
    float4 w0 = wr[0], w1 = wr[1];
    acc[0] += xv * w0.x; acc[1] += xv * w0.y; acc[2] += xv * w0.z; acc[3] += xv * w0.w;
    acc[4] += xv * w1.x; acc[5] += xv * w1.y; acc[6] += xv * w1.z; acc[7] += xv * w1.w;
  }
#pragma unroll
  for (int off = 32; off >= 1; off >>= 1){
#pragma unroll
    for (int e = 0; e < E; ++e) acc[e] += __shfl_xor(acc[e], off, 64);
  }
  if (lane == 0){
    float m = acc[0];
#pragma unroll
    for (int e = 1; e < E; ++e) m = fmaxf(m, acc[e]);
    float p[E], s = 0.f;
#pragma unroll
    for (int e = 0; e < E; ++e){ p[e] = __expf(acc[e] - m); s += p[e]; }
    float inv = 1.f / s;
    for (int e = 0; e < E; ++e) atomicAdd(&ps[e], p[e] * inv);
    int i1 = 0; float v1 = p[0];
#pragma unroll
    for (int e = 1; e < E; ++e) if (p[e] > v1){ v1 = p[e]; i1 = e; }
    int i2 = -1; float v2 = -1.f;
#pragma unroll
    for (int e = 0; e < E; ++e) if (e != i1 && p[e] > v2){ v2 = p[e]; i2 = e; }
    float rs = 1.f / (v1 + v2);
    topk_idx[2 * t] = i1; topk_idx[2 * t + 1] = i2;
    topk_w[2 * t] = v1 * rs; topk_w[2 * t + 1] = v2 * rs;
    atomicAdd(&counts[i1], 1); atomicAdd(&counts[i2], 1);
  }
  __syncthreads();
  if (tid < E) atomicAdd(&probs_sum[tid], ps[tid]);
}

// base[e] = prefix sum of counts padded to 128-multiples
__global__ void scan_kernel(const int* __restrict__ counts, int* __restrict__ base){
  if (threadIdx.x == 0){
    int off = 0;
    for (int e = 0; e < E; ++e){ base[e] = off; off += (counts[e] + 127) & ~127; }
  }
}

__global__ void scatter_kernel(const int* __restrict__ topk_idx, const float* __restrict__ topk_w,
                               const int* __restrict__ base, int* __restrict__ fill,
                               int* __restrict__ pair_token, int* __restrict__ pair_expert,
                               float* __restrict__ pair_score, int* __restrict__ token_pos)
{
  int t = blockIdx.x * 256 + threadIdx.x;
#pragma unroll
  for (int k = 0; k < 2; ++k){
    int e = topk_idx[2 * t + k];
    int pos = base[e] + atomicAdd(&fill[e], 1);
    pair_token[pos] = t;
    pair_expert[pos] = e;
    pair_score[pos] = topk_w[2 * t + k];
    token_pos[2 * t + k] = pos;
  }
}

// ---------------- conversions -----------------------------------------------
__global__ void __launch_bounds__(256) convert_x_kernel(const float* __restrict__ src, u16* __restrict__ dst){
  int i = blockIdx.x * 256 + threadIdx.x;
  float4 v = ((const float4*)src)[i];
  u32 lo = (u32)f2bf(v.x) | ((u32)f2bf(v.y) << 16);
  u32 hi = (u32)f2bf(v.z) | ((u32)f2bf(v.w) << 16);
  ((uint2*)dst)[i] = make_uint2(lo, hi);
}

// [R][C] f32 -> [C][R] bf16, batched over z
__global__ void __launch_bounds__(256) transpose_kernel(const float* __restrict__ src, u16* __restrict__ dst,
                                                        int R, int C){
  __shared__ float tile[32][33];
  long zoff = (long)blockIdx.z * R * C;
  int tx = threadIdx.x & 31, ty = threadIdx.x >> 5;
  int c = blockIdx.x * 32 + tx;
  int rb = blockIdx.y * 32;
#pragma unroll
  for (int j = 0; j < 4; ++j)
    tile[ty + j * 8][tx] = src[zoff + (long)(rb + ty + j * 8) * C + c];
  __syncthreads();
#pragma unroll
  for (int j = 0; j < 4; ++j){
    int cc = blockIdx.x * 32 + ty + j * 8;
    dst[zoff + (long)cc * R + rb + tx] = f2bf(tile[tx][ty + j * 8]);
  }
}

// ---------------- fused gate+up GEMM with SwiGLU epilogue --------------------
// C[M x N] tiles: BM=128, BN=64, BK=64. 4 waves in 2x2; wave tile 64x32.
// A row-major [.][K] bf16 (optional gather), Bg/Bu are B^T [N][K] bf16.
__global__ void __launch_bounds__(256) gateup_kernel(
    const u16* __restrict__ A, const u16* __restrict__ Bg, const u16* __restrict__ Bu,
    u16* __restrict__ Hout, int N, int K,
    const int* __restrict__ gather, const int* __restrict__ pexp, long bstride)
{
  __shared__ u16 As[128 * 64];
  __shared__ u16 Bgs[64 * 64];
  __shared__ u16 Bus[64 * 64];
  int tid = threadIdx.x, lane = tid & 63, wave = tid >> 6;
  int wy = wave >> 1, wx = wave & 1;
  int m0 = blockIdx.y * 128, n0 = blockIdx.x * 64;
  int e = pexp ? pexp[m0] : 0;
  const u16* bg = Bg + (long)e * bstride;
  const u16* bu = Bu + (long)e * bstride;

  f32x4 accG[4][2], accU[4][2];
#pragma unroll
  for (int i = 0; i < 4; ++i)
#pragma unroll
    for (int j = 0; j < 2; ++j)
#pragma unroll
      for (int r = 0; r < 4; ++r){ accG[i][j][r] = 0.f; accU[i][j][r] = 0.f; }

  for (int k0 = 0; k0 < K; k0 += 64){
    stage_tile<128>(A, K, k0, m0, gather, As, wave, lane);
    stage_tile<64>(bg, K, k0, n0, nullptr, Bgs, wave, lane);
    stage_tile<64>(bu, K, k0, n0, nullptr, Bus, wave, lane);
    __syncthreads();
#pragma unroll
    for (int ks = 0; ks < 2; ++ks){
      int ko = ks * 32 + (lane >> 4) * 8;
      short8 a[4], g2[2], u2[2];
#pragma unroll
      for (int mt = 0; mt < 4; ++mt)
        a[mt] = *(const short8*)(As + (wy * 64 + mt * 16 + (lane & 15)) * 64 + ko);
#pragma unroll
      for (int nt = 0; nt < 2; ++nt){
        g2[nt] = *(const short8*)(Bgs + (wx * 32 + nt * 16 + (lane & 15)) * 64 + ko);
        u2[nt] = *(const short8*)(Bus + (wx * 32 + nt * 16 + (lane & 15)) * 64 + ko);
      }
#pragma unroll
      for (int mt = 0; mt < 4; ++mt)
#pragma unroll
        for (int nt = 0; nt < 2; ++nt){
          accG[mt][nt] = __builtin_amdgcn_mfma_f32_16x16x32_bf16(a[mt], g2[nt], accG[mt][nt], 0, 0, 0);
          accU[mt][nt] = __builtin_amdgcn_mfma_f32_16x16x32_bf16(a[mt], u2[nt], accU[mt][nt], 0, 0, 0);
        }
    }
    __syncthreads();
  }
  // epilogue: h = silu(g)*u, bf16 store. C/D map: col=lane&15, row=(lane>>4)*4+r
  int row0 = m0 + wy * 64, col0 = n0 + wx * 32;
#pragma unroll
  for (int mt = 0; mt < 4; ++mt)
#pragma unroll
    for (int nt = 0; nt < 2; ++nt)
#pragma unroll
      for (int r = 0; r < 4; ++r){
        int row = row0 + mt * 16 + (lane >> 4) * 4 + r;
        int col = col0 + nt * 16 + (lane & 15);
        float g = accG[mt][nt][r], u = accU[mt][nt][r];
        float h = g / (1.f + __expf(-g)) * u;
        Hout[(long)row * N + col] = f2bf(h);
      }
}

// ---------------- routed down GEMM: rout[pair] = score * (hr @ WdT[e]) -------
// BM=128, BN=128, BK=64; wave tile 64x64.
__global__ void __launch_bounds__(256) down_routed_kernel(
    const u16* __restrict__ A, const u16* __restrict__ B, u16* __restrict__ rout,
    const float* __restrict__ pair_score, const int* __restrict__ pexp)
{
  __shared__ u16 As[128 * 64];
  __shared__ u16 Bs[128 * 64];
  int tid = threadIdx.x, lane = tid & 63, wave = tid >> 6;
  int wy = wave >> 1, wx = wave & 1;
  int m0 = blockIdx.y * 128, n0 = blockIdx.x * 128;
  int e = pexp[m0];
  const u16* b = B + (long)e * (H * D);

  f32x4 acc[4][4];
#pragma unroll
  for (int i = 0; i < 4; ++i)
#pragma unroll
    for (int j = 0; j < 4; ++j)
#pragma unroll
      for (int r = 0; r < 4; ++r) acc[i][j][r] = 0.f;

  for (int k0 = 0; k0 < D; k0 += 64){
    stage_tile<128>(A, D, k0, m0, nullptr, As, wave, lane);
    stage_tile<128>(b, D, k0, n0, nullptr, Bs, wave, lane);
    __syncthreads();
#pragma unroll
    for (int ks = 0; ks < 2; ++ks){
      int ko = ks * 32 + (lane >> 4) * 8;
      short8 a[4], bv[4];
#pragma unroll
      for (int mt = 0; mt < 4; ++mt)
        a[mt] = *(const short8*)(As + (wy * 64 + mt * 16 + (lane & 15)) * 64 + ko);
#pragma unroll
      for (int nt = 0; nt < 4; ++nt)
        bv[nt] = *(const short8*)(Bs + (wx * 64 + nt * 16 + (lane & 15)) * 64 + ko);
#pragma unroll
      for (int mt = 0; mt < 4; ++mt)
#pragma unroll
        for (int nt = 0; nt < 4; ++nt)
          acc[mt][nt] = __builtin_amdgcn_mfma_f32_16x16x32_bf16(a[mt], bv[nt], acc[mt][nt], 0, 0, 0);
    }
    __syncthreads();
  }
#pragma unroll
  for (int mt = 0; mt < 4; ++mt)
#pragma unroll
    for (int r = 0; r < 4; ++r){
      int row = m0 + wy * 64 + mt * 16 + (lane >> 4) * 4 + r;
      float s = pair_score[row];
      long rbase = (long)row * H;
#pragma unroll
      for (int nt = 0; nt < 4; ++nt){
        int col = n0 + wx * 64 + nt * 16 + (lane & 15);
        rout[rbase + col] = f2bf(s * acc[mt][nt][r]);
      }
    }
}

// ---------------- shared down GEMM + combine: out = hs@WsdT + rout0 + rout1 --
__global__ void __launch_bounds__(256) down_shared_kernel(
    const u16* __restrict__ A, const u16* __restrict__ B,
    const u16* __restrict__ rout, const int* __restrict__ token_pos,
    float* __restrict__ out)
{
  __shared__ u16 As[128 * 64];
  __shared__ u16 Bs[128 * 64];
  int tid = threadIdx.x, lane = tid & 63, wave = tid >> 6;
  int wy = wave >> 1, wx = wave & 1;
  int m0 = blockIdx.y * 128, n0 = blockIdx.x * 128;

  f32x4 acc[4][4];
#pragma unroll
  for (int i = 0; i < 4; ++i)
#pragma unroll
    for (int j = 0; j < 4; ++j)
#pragma unroll
      for (int r = 0; r < 4; ++r) acc[i][j][r] = 0.f;

  for (int k0 = 0; k0 < DS; k0 += 64){
    stage_tile<128>(A, DS, k0, m0, nullptr, As, wave, lane);
    stage_tile<128>(B, DS, k0, n0, nullptr, Bs, wave, lane);
    __syncthreads();
#pragma unroll
    for (int ks = 0; ks < 2; ++ks){
      int ko = ks * 32 + (lane >> 4) * 8;
      short8 a[4], bv[4];
#pragma unroll
      for (int mt = 0; mt < 4; ++mt)
        a[mt] = *(const short8*)(As + (wy * 64 + mt * 16 + (lane & 15)) * 64 + ko);
#pragma unroll
      for (int nt = 0; nt < 4; ++nt)
        bv[nt] = *(const short8*)(Bs + (wx * 64 + nt * 16 + (lane & 15)) * 64 + ko);
#pragma unroll
      for (int mt = 0; mt < 4; ++mt)
#pragma unroll
        for (int nt = 0; nt < 4; ++nt)
          acc[mt][nt] = __builtin_amdgcn_mfma_f32_16x16x32_bf16(a[mt], bv[nt], acc[mt][nt], 0, 0, 0);
    }
    __syncthreads();
  }
#pragma unroll
  for (int mt = 0; mt < 4; ++mt)
#pragma unroll
    for (int r = 0; r < 4; ++r){
      int row = m0 + wy * 64 + mt * 16 + (lane >> 4) * 4 + r;
      int p0 = token_pos[2 * row], p1 = token_pos[2 * row + 1];
      long o = (long)row * H;
#pragma unroll
      for (int nt = 0; nt < 4; ++nt){
        int col = n0 + wx * 64 + nt * 16 + (lane & 15);
        out[o + col] = acc[mt][nt][r]
                     + bf2f(rout[(long)p0 * H + col])
                     + bf2f(rout[(long)p1 * H + col]);
      }
    }
}

__global__ void aux_kernel(const float* __restrict__ probs_sum, float* __restrict__ out_aux){
  if (threadIdx.x == 0){
    float a = 0.f;
    for (int e = 0; e < E; ++e){
      float m = probs_sum[e] * (1.f / (float)T);
      a += m * m;
    }
    out_aux[0] = (float)E * a;
  }
}

// ---------------- launch -----------------------------------------------------
extern "C" void kernel_launch(void* const* d_in, const int* in_sizes, int n_in,
                              void* d_out, int out_size, void* d_ws, size_t ws_size,
                              hipStream_t stream)
{
  (void)in_sizes; (void)n_in; (void)out_size; (void)ws_size;
  const float* x   = (const float*)d_in[0];
  const float* Wr  = (const float*)d_in[1];
  const float* Wg  = (const float*)d_in[2];
  const float* Wu  = (const float*)d_in[3];
  const float* Wd  = (const float*)d_in[4];
  const float* Wsg = (const float*)d_in[5];
  const float* Wsu = (const float*)d_in[6];
  const float* Wsd = (const float*)d_in[7];
  float* out = (float*)d_out;

  char* ws = (char*)d_ws;
  size_t off = 0;
  auto alloc = [&](size_t bytes) -> void* {
    void* p = ws + off; off += (bytes + 255) & ~(size_t)255; return p;
  };
  u16* xb   = (u16*)alloc((size_t)T * H * 2);
  u16* WsgT = (u16*)alloc((size_t)DS * H * 2);
  u16* WsuT = (u16*)alloc((size_t)DS * H * 2);
  u16* WsdT = (u16*)alloc((size_t)H * DS * 2);
  u16* WgT  = (u16*)alloc((size_t)E * D * H * 2);
  u16* WuT  = (u16*)alloc((size_t)E * D * H * 2);
  u16* WdT  = (u16*)alloc((size_t)E * H * D * 2);
  u16* hs   = (u16*)alloc((size_t)T * DS * 2);
  u16* hr   = (u16*)alloc((size_t)PAIR_CAP * D * 2);
  u16* rout = (u16*)alloc((size_t)PAIR_CAP * H * 2);
  int*   topk_idx  = (int*)alloc((size_t)T * 2 * 4);
  float* topk_w    = (float*)alloc((size_t)T * 2 * 4);
  int*   token_pos = (int*)alloc((size_t)T * 2 * 4);
  // the following region is zero-initialized in one memset (keep contiguous)
  char* zbase = ws + off;
  int*   pair_token  = (int*)alloc((size_t)PAIR_CAP * 4);
  int*   pair_expert = (int*)alloc((size_t)PAIR_CAP * 4);
  float* pair_score  = (float*)alloc((size_t)PAIR_CAP * 4);
  int*   meta        = (int*)alloc(256);
  int*   counts    = meta;
  int*   fill      = meta + 8;
  int*   base      = meta + 16;
  float* probs_sum = (float*)(meta + 24);
  size_t zbytes = (size_t)((char*)meta - zbase) + 256;

  hipMemsetAsync(zbase, 0, zbytes, stream);

  convert_x_kernel<<<T * H / 4 / 256, 256, 0, stream>>>(x, xb);
  transpose_kernel<<<dim3(DS / 32, H / 32, 1), 256, 0, stream>>>(Wsg, WsgT, H, DS);
  transpose_kernel<<<dim3(DS / 32, H / 32, 1), 256, 0, stream>>>(Wsu, WsuT, H, DS);
  transpose_kernel<<<dim3(H / 32, DS / 32, 1), 256, 0, stream>>>(Wsd, WsdT, DS, H);
  transpose_kernel<<<dim3(D / 32, H / 32, E), 256, 0, stream>>>(Wg, WgT, H, D);
  transpose_kernel<<<dim3(D / 32, H / 32, E), 256, 0, stream>>>(Wu, WuT, H, D);
  transpose_kernel<<<dim3(H / 32, D / 32, E), 256, 0, stream>>>(Wd, WdT, D, H);

  router_kernel<<<T / 4, 256, 0, stream>>>(x, Wr, topk_idx, topk_w, counts, probs_sum);
  scan_kernel<<<1, 64, 0, stream>>>(counts, base);
  scatter_kernel<<<T / 256, 256, 0, stream>>>(topk_idx, topk_w, base, fill,
                                              pair_token, pair_expert, pair_score, token_pos);

  // shared gate+up -> hs [T x DS]
  gateup_kernel<<<dim3(DS / 64, T / 128), 256, 0, stream>>>(
      xb, WsgT, WsuT, hs, DS, H, nullptr, nullptr, 0);
  // routed gate+up -> hr [PAIR_CAP x D] (A gathered by pair_token)
  gateup_kernel<<<dim3(D / 64, MT_ROUTED), 256, 0, stream>>>(
      xb, WgT, WuT, hr, D, H, pair_token, pair_expert, (long)D * H);
  // routed down -> rout [PAIR_CAP x H], scaled by pair score
  down_routed_kernel<<<dim3(H / 128, MT_ROUTED), 256, 0, stream>>>(
      hr, WdT, rout, pair_score, pair_expert);
  // shared down + combine -> out [T x H] fp32
  down_shared_kernel<<<dim3(H / 128, T / 128), 256, 0, stream>>>(
      hs, WsdT, rout, token_pos, out);

  aux_kernel<<<1, 64, 0, stream>>>(probs_sum, out + (size_t)T * H);
}

// Round 2
// 387.379 us; speedup vs baseline: 1.6722x; 1.6722x over previous
//
#include <hip/hip_runtime.h>

// MoE forward: shared SwiGLU expert + top-2/8 routed SwiGLU experts + aux loss.
// bf16 MFMA (16x16x32) GEMMs, m97-style 128-tile with global_load_lds width-16
// staging; routed experts via padded per-expert segments (fixed grid, graph-
// capture safe). R1: routing path is 100% atomic-free (R0 had 32k same-line
// device atomics -> 200us serialized router).

typedef unsigned short u16;
typedef unsigned int   u32;
typedef short short8 __attribute__((ext_vector_type(8)));
typedef float f32x4  __attribute__((ext_vector_type(4)));

#define AS1 __attribute__((address_space(1)))
#define AS3 __attribute__((address_space(3)))

constexpr int T  = 8192;
constexpr int H  = 1024;
constexpr int E  = 8;
constexpr int D  = 512;
constexpr int DS = 1024;          // shared expert width
constexpr int PAIR_CAP  = 17408;  // 136 * 128 >= 16384 + 8*127
constexpr int MT_ROUTED = 136;    // routed m-tiles (128 rows each)
constexpr int RB = 256;           // router blocks (32 tokens each)

__device__ __forceinline__ u16 f2bf(float f){
  u32 u = __builtin_bit_cast(u32, f);
  u += 0x7fffu + ((u >> 16) & 1u);   // round-to-nearest-even
  return (u16)(u >> 16);
}
__device__ __forceinline__ float bf2f(u16 h){
  u32 u = ((u32)h) << 16;
  return __builtin_bit_cast(float, u);
}

// async global->LDS, 16B per lane. LDS dest = wave-uniform base + lane*16.
__device__ __forceinline__ void gl_lds16(const u16* g, u16* l){
  __builtin_amdgcn_global_load_lds((const AS1 void*)g, (AS3 void*)l, 16, 0, 0);
}

// Stage a ROWS x 64(bf16) tile into LDS (row-major, 64-elem row stride).
template<int ROWS>
__device__ __forceinline__ void stage_tile(const u16* __restrict__ gbase, int ld, int k0,
                                           int rowbase, const int* __restrict__ gather,
                                           u16* lds, int wave, int lane){
  constexpr int ISS = ROWS / 32;   // issues per wave (4 waves total)
  int lr = lane >> 3, ch = lane & 7;
#pragma unroll
  for (int j = 0; j < ISS; ++j){
    int idx = wave * ISS + j;
    int row = idx * 8 + lr;
    int grow = gather ? gather[rowbase + row] : (rowbase + row);
    const u16* g = gbase + (long)grow * ld + k0 + ch * 8;
    gl_lds16(g, lds + idx * 512);  // 512 u16 = 1024B per issue, wave-uniform
  }
}

// ---------------- router: logits -> softmax -> top2 -> per-block partials ----
// 256 blocks x 4 waves x 8 tokens. No global atomics.
__global__ void __launch_bounds__(256) router_kernel(
    const float* __restrict__ x, const float* __restrict__ Wr,
    int* __restrict__ topk_idx, float* __restrict__ topk_w,
    int* __restrict__ partial_hist, float* __restrict__ partial_probs)
{
  __shared__ int   hist_s[4][8];
  __shared__ float ps_s[4][8];
  int tid = threadIdx.x, lane = tid & 63, wv = tid >> 6;
  int   histl[8] = {0,0,0,0,0,0,0,0};
  float psl[8]   = {0.f,0.f,0.f,0.f,0.f,0.f,0.f,0.f};

  for (int it = 0; it < 8; ++it){
    int t = blockIdx.x * 32 + wv * 8 + it;
    const float4* xr = (const float4*)(x + (long)t * H);
    float acc[8];
#pragma unroll
    for (int e = 0; e < 8; ++e) acc[e] = 0.f;
#pragma unroll
    for (int i = 0; i < 4; ++i){
      float4 xv = xr[i * 64 + lane];
      int h0 = i * 256 + lane * 4;
#pragma unroll
      for (int j = 0; j < 4; ++j){
        float xs = (j == 0) ? xv.x : (j == 1) ? xv.y : (j == 2) ? xv.z : xv.w;
        const float4* wr = (const float4*)(Wr + (long)(h0 + j) * E);
        float4 w0 = wr[0], w1 = wr[1];
        acc[0] += xs * w0.x; acc[1] += xs * w0.y; acc[2] += xs * w0.z; acc[3] += xs * w0.w;
        acc[4] += xs * w1.x; acc[5] += xs * w1.y; acc[6] += xs * w1.z; acc[7] += xs * w1.w;
      }
    }
#pragma unroll
    for (int off = 32; off >= 1; off >>= 1){
#pragma unroll
      for (int e = 0; e < 8; ++e) acc[e] += __shfl_xor(acc[e], off, 64);
    }
    if (lane == 0){
      float m = acc[0];
#pragma unroll
      for (int e = 1; e < 8; ++e) m = fmaxf(m, acc[e]);
      float p[8], s = 0.f;
#pragma unroll
      for (int e = 0; e < 8; ++e){ p[e] = __expf(acc[e] - m); s += p[e]; }
      float inv = 1.f / s;
#pragma unroll
      for (int e = 0; e < 8; ++e) psl[e] += p[e] * inv;
      int i1 = 0; float v1 = p[0];
#pragma unroll
      for (int e = 1; e < 8; ++e) if (p[e] > v1){ v1 = p[e]; i1 = e; }
      int i2 = -1; float v2 = -1.f;
#pragma unroll
      for (int e = 0; e < 8; ++e) if (e != i1 && p[e] > v2){ v2 = p[e]; i2 = e; }
      float rs = 1.f / (v1 + v2);
      topk_idx[2 * t] = i1; topk_idx[2 * t + 1] = i2;
      topk_w[2 * t] = v1 * rs; topk_w[2 * t + 1] = v2 * rs;
      histl[i1]++; histl[i2]++;
    }
  }
  if (lane == 0){
#pragma unroll
    for (int e = 0; e < 8; ++e){ hist_s[wv][e] = histl[e]; ps_s[wv][e] = psl[e]; }
  }
  __syncthreads();
  if (tid < 8){
    int hs = 0; float ps = 0.f;
#pragma unroll
    for (int w = 0; w < 4; ++w){ hs += hist_s[w][tid]; ps += ps_s[w][tid]; }
    partial_hist[blockIdx.x * 8 + tid]  = hs;
    partial_probs[blockIdx.x * 8 + tid] = ps;
  }
}

// ---------------- scan: padded bases + per-block offsets + aux loss ----------
__global__ void __launch_bounds__(64) scan_kernel(
    const int* __restrict__ partial_hist, const float* __restrict__ partial_probs,
    int* __restrict__ block_offset, float* __restrict__ out_aux)
{
  __shared__ int   csum[8][8];     // [chunk][expert], chunk = 32 blocks
  __shared__ float cps[8][8];
  __shared__ int   cbase[8][8];
  __shared__ int   base_s[8];
  int tid = threadIdx.x, e = tid & 7, c = tid >> 3;
  int s = 0; float f = 0.f;
  for (int b = c * 32; b < c * 32 + 32; ++b){
    s += partial_hist[b * 8 + e]; f += partial_probs[b * 8 + e];
  }
  csum[c][e] = s; cps[c][e] = f;
  __syncthreads();
  if (tid < 8){
    int tot = 0;
    for (int cc = 0; cc < 8; ++cc){ cbase[cc][tid] = tot; tot += csum[cc][tid]; }
    csum[0][tid] = tot;            // column total (cbase already captured)
  }
  __syncthreads();
  if (tid == 0){
    int off = 0;
    for (int ee = 0; ee < 8; ++ee){ base_s[ee] = off; off += (csum[0][ee] + 127) & ~127; }
    float a = 0.f;
    for (int ee = 0; ee < 8; ++ee){
      float ps = 0.f;
      for (int cc = 0; cc < 8; ++cc) ps += cps[cc][ee];
      float m = ps * (1.f / (float)T);
      a += m * m;
    }
    out_aux[0] = (float)E * a;
  }
  __syncthreads();
  int run = base_s[e] + cbase[c][e];
  for (int b = c * 32; b < c * 32 + 32; ++b){
    block_offset[b * 8 + e] = run;
    run += partial_hist[b * 8 + e];
  }
}

// ---------------- scatter: ballot-ranked, atomic-free ------------------------
// 256 blocks x 1 wave; block b covers pairs [b*64, b*64+64) = tokens [b*32,+32)
__global__ void __launch_bounds__(64) scatter_kernel(
    const int* __restrict__ topk_idx, const float* __restrict__ topk_w,
    const int* __restrict__ block_offset,
    int* __restrict__ pair_token, int* __restrict__ pair_expert,
    float* __restrict__ pair_score, int* __restrict__ token_pos)
{
  int lane = threadIdx.x, b = blockIdx.x;
  int idx = b * 64 + lane;
  int t = idx >> 1;
  int e = topk_idx[idx];
  float w = topk_w[idx];
  unsigned long long below = lane ? ((1ull << lane) - 1ull) : 0ull;
  int rank = 0, basee = 0;
#pragma unroll
  for (int ee = 0; ee < 8; ++ee){
    unsigned long long m = __ballot(e == ee);
    if (e == ee){ rank = __popcll(m & below); basee = block_offset[b * 8 + ee]; }
  }
  int pos = basee + rank;
  pair_token[pos] = t;
  pair_expert[pos] = e;
  pair_score[pos] = w;
  token_pos[idx] = pos;
}

// ---------------- conversions -----------------------------------------------
__global__ void __launch_bounds__(256) convert_x_kernel(const float* __restrict__ src, u16* __restrict__ dst){
  int i = blockIdx.x * 256 + threadIdx.x;
  float4 v = ((const float4*)src)[i];
  u32 lo = (u32)f2bf(v.x) | ((u32)f2bf(v.y) << 16);
  u32 hi = (u32)f2bf(v.z) | ((u32)f2bf(v.w) << 16);
  ((uint2*)dst)[i] = make_uint2(lo, hi);
}

// [R][C] f32 -> [C][R] bf16, batched over z
__global__ void __launch_bounds__(256) transpose_kernel(const float* __restrict__ src, u16* __restrict__ dst,
                                                        int R, int C){
  __shared__ float tile[32][33];
  long zoff = (long)blockIdx.z * R * C;
  int tx = threadIdx.x & 31, ty = threadIdx.x >> 5;
  int c = blockIdx.x * 32 + tx;
  int rb = blockIdx.y * 32;
#pragma unroll
  for (int j = 0; j < 4; ++j)
    tile[ty + j * 8][tx] = src[zoff + (long)(rb + ty + j * 8) * C + c];
  __syncthreads();
#pragma unroll
  for (int j = 0; j < 4; ++j){
    int cc = blockIdx.x * 32 + ty + j * 8;
    dst[zoff + (long)cc * R + rb + tx] = f2bf(tile[tx][ty + j * 8]);
  }
}

// ---------------- fused gate+up GEMM with SwiGLU epilogue --------------------
// BM=128, BN=64, BK=64. 4 waves in 2x2; wave tile 64x32.
__global__ void __launch_bounds__(256) gateup_kernel(
    const u16* __restrict__ A, const u16* __restrict__ Bg, const u16* __restrict__ Bu,
    u16* __restrict__ Hout, int N, int K,
    const int* __restrict__ gather, const int* __restrict__ pexp, long bstride)
{
  __shared__ u16 As[128 * 64];
  __shared__ u16 Bgs[64 * 64];
  __shared__ u16 Bus[64 * 64];
  int tid = threadIdx.x, lane = tid & 63, wave = tid >> 6;
  int wy = wave >> 1, wx = wave & 1;
  int m0 = blockIdx.y * 128, n0 = blockIdx.x * 64;
  int e = pexp ? pexp[m0] : 0;
  const u16* bg = Bg + (long)e * bstride;
  const u16* bu = Bu + (long)e * bstride;

  f32x4 accG[4][2], accU[4][2];
#pragma unroll
  for (int i = 0; i < 4; ++i)
#pragma unroll
    for (int j = 0; j < 2; ++j)
#pragma unroll
      for (int r = 0; r < 4; ++r){ accG[i][j][r] = 0.f; accU[i][j][r] = 0.f; }

  for (int k0 = 0; k0 < K; k0 += 64){
    stage_tile<128>(A, K, k0, m0, gather, As, wave, lane);
    stage_tile<64>(bg, K, k0, n0, nullptr, Bgs, wave, lane);
    stage_tile<64>(bu, K, k0, n0, nullptr, Bus, wave, lane);
    __syncthreads();
#pragma unroll
    for (int ks = 0; ks < 2; ++ks){
      int ko = ks * 32 + (lane >> 4) * 8;
      short8 a[4], g2[2], u2[2];
#pragma unroll
      for (int mt = 0; mt < 4; ++mt)
        a[mt] = *(const short8*)(As + (wy * 64 + mt * 16 + (lane & 15)) * 64 + ko);
#pragma unroll
      for (int nt = 0; nt < 2; ++nt){
        g2[nt] = *(const short8*)(Bgs + (wx * 32 + nt * 16 + (lane & 15)) * 64 + ko);
        u2[nt] = *(const short8*)(Bus + (wx * 32 + nt * 16 + (lane & 15)) * 64 + ko);
      }
#pragma unroll
      for (int mt = 0; mt < 4; ++mt)
#pragma unroll
        for (int nt = 0; nt < 2; ++nt){
          accG[mt][nt] = __builtin_amdgcn_mfma_f32_16x16x32_bf16(a[mt], g2[nt], accG[mt][nt], 0, 0, 0);
          accU[mt][nt] = __builtin_amdgcn_mfma_f32_16x16x32_bf16(a[mt], u2[nt], accU[mt][nt], 0, 0, 0);
        }
    }
    __syncthreads();
  }
  int row0 = m0 + wy * 64, col0 = n0 + wx * 32;
#pragma unroll
  for (int mt = 0; mt < 4; ++mt)
#pragma unroll
    for (int nt = 0; nt < 2; ++nt)
#pragma unroll
      for (int r = 0; r < 4; ++r){
        int row = row0 + mt * 16 + (lane >> 4) * 4 + r;
        int col = col0 + nt * 16 + (lane & 15);
        float g = accG[mt][nt][r], u = accU[mt][nt][r];
        float h = g / (1.f + __expf(-g)) * u;
        Hout[(long)row * N + col] = f2bf(h);
      }
}

// ---------------- routed down GEMM: rout[pair] = score * (hr @ WdT[e]) -------
__global__ void __launch_bounds__(256) down_routed_kernel(
    const u16* __restrict__ A, const u16* __restrict__ B, u16* __restrict__ rout,
    const float* __restrict__ pair_score, const int* __restrict__ pexp)
{
  __shared__ u16 As[128 * 64];
  __shared__ u16 Bs[128 * 64];
  int tid = threadIdx.x, lane = tid & 63, wave = tid >> 6;
  int wy = wave >> 1, wx = wave & 1;
  int m0 = blockIdx.y * 128, n0 = blockIdx.x * 128;
  int e = pexp[m0];
  const u16* b = B + (long)e * (H * D);

  f32x4 acc[4][4];
#pragma unroll
  for (int i = 0; i < 4; ++i)
#pragma unroll
    for (int j = 0; j < 4; ++j)
#pragma unroll
      for (int r = 0; r < 4; ++r) acc[i][j][r] = 0.f;

  for (int k0 = 0; k0 < D; k0 += 64){
    stage_tile<128>(A, D, k0, m0, nullptr, As, wave, lane);
    stage_tile<128>(b, D, k0, n0, nullptr, Bs, wave, lane);
    __syncthreads();
#pragma unroll
    for (int ks = 0; ks < 2; ++ks){
      int ko = ks * 32 + (lane >> 4) * 8;
      short8 a[4], bv[4];
#pragma unroll
      for (int mt = 0; mt < 4; ++mt)
        a[mt] = *(const short8*)(As + (wy * 64 + mt * 16 + (lane & 15)) * 64 + ko);
#pragma unroll
      for (int nt = 0; nt < 4; ++nt)
        bv[nt] = *(const short8*)(Bs + (wx * 64 + nt * 16 + (lane & 15)) * 64 + ko);
#pragma unroll
      for (int mt = 0; mt < 4; ++mt)
#pragma unroll
        for (int nt = 0; nt < 4; ++nt)
          acc[mt][nt] = __builtin_amdgcn_mfma_f32_16x16x32_bf16(a[mt], bv[nt], acc[mt][nt], 0, 0, 0);
    }
    __syncthreads();
  }
#pragma unroll
  for (int mt = 0; mt < 4; ++mt)
#pragma unroll
    for (int r = 0; r < 4; ++r){
      int row = m0 + wy * 64 + mt * 16 + (lane >> 4) * 4 + r;
      float s = pair_score[row];
      long rbase = (long)row * H;
#pragma unroll
      for (int nt = 0; nt < 4; ++nt){
        int col = n0 + wx * 64 + nt * 16 + (lane & 15);
        rout[rbase + col] = f2bf(s * acc[mt][nt][r]);
      }
    }
}

// ---------------- shared down GEMM + combine ---------------------------------
__global__ void __launch_bounds__(256) down_shared_kernel(
    const u16* __restrict__ A, const u16* __restrict__ B,
    const u16* __restrict__ rout, const int* __restrict__ token_pos,
    float* __restrict__ out)
{
  __shared__ u16 As[128 * 64];
  __shared__ u16 Bs[128 * 64];
  int tid = threadIdx.x, lane = tid & 63, wave = tid >> 6;
  int wy = wave >> 1, wx = wave & 1;
  int m0 = blockIdx.y * 128, n0 = blockIdx.x * 128;

  f32x4 acc[4][4];
#pragma unroll
  for (int i = 0; i < 4; ++i)
#pragma unroll
    for (int j = 0; j < 4; ++j)
#pragma unroll
      for (int r = 0; r < 4; ++r) acc[i][j][r] = 0.f;

  for (int k0 = 0; k0 < DS; k0 += 64){
    stage_tile<128>(A, DS, k0, m0, nullptr, As, wave, lane);
    stage_tile<128>(B, DS, k0, n0, nullptr, Bs, wave, lane);
    __syncthreads();
#pragma unroll
    for (int ks = 0; ks < 2; ++ks){
      int ko = ks * 32 + (lane >> 4) * 8;
      short8 a[4], bv[4];
#pragma unroll
      for (int mt = 0; mt < 4; ++mt)
        a[mt] = *(const short8*)(As + (wy * 64 + mt * 16 + (lane & 15)) * 64 + ko);
#pragma unroll
      for (int nt = 0; nt < 4; ++nt)
        bv[nt] = *(const short8*)(Bs + (wx * 64 + nt * 16 + (lane & 15)) * 64 + ko);
#pragma unroll
      for (int mt = 0; mt < 4; ++mt)
#pragma unroll
        for (int nt = 0; nt < 4; ++nt)
          acc[mt][nt] = __builtin_amdgcn_mfma_f32_16x16x32_bf16(a[mt], bv[nt], acc[mt][nt], 0, 0, 0);
    }
    __syncthreads();
  }
#pragma unroll
  for (int mt = 0; mt < 4; ++mt)
#pragma unroll
    for (int r = 0; r < 4; ++r){
      int row = m0 + wy * 64 + mt * 16 + (lane >> 4) * 4 + r;
      int p0 = token_pos[2 * row], p1 = token_pos[2 * row + 1];
      long o = (long)row * H;
#pragma unroll
      for (int nt = 0; nt < 4; ++nt){
        int col = n0 + wx * 64 + nt * 16 + (lane & 15);
        out[o + col] = acc[mt][nt][r]
                     + bf2f(rout[(long)p0 * H + col])
                     + bf2f(rout[(long)p1 * H + col]);
      }
    }
}

// ---------------- launch -----------------------------------------------------
extern "C" void kernel_launch(void* const* d_in, const int* in_sizes, int n_in,
                              void* d_out, int out_size, void* d_ws, size_t ws_size,
                              hipStream_t stream)
{
  (void)in_sizes; (void)n_in; (void)out_size; (void)ws_size;
  const float* x   = (const float*)d_in[0];
  const float* Wr  = (const float*)d_in[1];
  const float* Wg  = (const float*)d_in[2];
  const float* Wu  = (const float*)d_in[3];
  const float* Wd  = (const float*)d_in[4];
  const float* Wsg = (const float*)d_in[5];
  const float* Wsu = (const float*)d_in[6];
  const float* Wsd = (const float*)d_in[7];
  float* out = (float*)d_out;

  char* ws = (char*)d_ws;
  size_t off = 0;
  auto alloc = [&](size_t bytes) -> void* {
    void* p = ws + off; off += (bytes + 255) & ~(size_t)255; return p;
  };
  u16* xb   = (u16*)alloc((size_t)T * H * 2);
  u16* WsgT = (u16*)alloc((size_t)DS * H * 2);
  u16* WsuT = (u16*)alloc((size_t)DS * H * 2);
  u16* WsdT = (u16*)alloc((size_t)H * DS * 2);
  u16* WgT  = (u16*)alloc((size_t)E * D * H * 2);
  u16* WuT  = (u16*)alloc((size_t)E * D * H * 2);
  u16* WdT  = (u16*)alloc((size_t)E * H * D * 2);
  u16* hs   = (u16*)alloc((size_t)T * DS * 2);
  u16* hr   = (u16*)alloc((size_t)PAIR_CAP * D * 2);
  u16* rout = (u16*)alloc((size_t)PAIR_CAP * H * 2);
  int*   topk_idx  = (int*)alloc((size_t)T * 2 * 4);
  float* topk_w    = (float*)alloc((size_t)T * 2 * 4);
  int*   token_pos = (int*)alloc((size_t)T * 2 * 4);
  int*   partial_hist  = (int*)alloc((size_t)RB * 8 * 4);
  float* partial_probs = (float*)alloc((size_t)RB * 8 * 4);
  int*   block_offset  = (int*)alloc((size_t)RB * 8 * 4);
  // zero-initialized region (dummy pair slots must read as 0)
  char* zbase = ws + off;
  int*   pair_token  = (int*)alloc((size_t)PAIR_CAP * 4);
  int*   pair_expert = (int*)alloc((size_t)PAIR_CAP * 4);
  float* pair_score  = (float*)alloc((size_t)PAIR_CAP * 4);
  size_t zbytes = (size_t)((ws + off) - zbase);

  hipMemsetAsync(zbase, 0, zbytes, stream);

  convert_x_kernel<<<T * H / 4 / 256, 256, 0, stream>>>(x, xb);
  transpose_kernel<<<dim3(DS / 32, H / 32, 1), 256, 0, stream>>>(Wsg, WsgT, H, DS);
  transpose_kernel<<<dim3(DS / 32, H / 32, 1), 256, 0, stream>>>(Wsu, WsuT, H, DS);
  transpose_kernel<<<dim3(H / 32, DS / 32, 1), 256, 0, stream>>>(Wsd, WsdT, DS, H);
  transpose_kernel<<<dim3(D / 32, H / 32, E), 256, 0, stream>>>(Wg, WgT, H, D);
  transpose_kernel<<<dim3(D / 32, H / 32, E), 256, 0, stream>>>(Wu, WuT, H, D);
  transpose_kernel<<<dim3(H / 32, D / 32, E), 256, 0, stream>>>(Wd, WdT, D, H);

  router_kernel<<<RB, 256, 0, stream>>>(x, Wr, topk_idx, topk_w, partial_hist, partial_probs);
  scan_kernel<<<1, 64, 0, stream>>>(partial_hist, partial_probs, block_offset,
                                    out + (size_t)T * H);
  scatter_kernel<<<RB, 64, 0, stream>>>(topk_idx, topk_w, block_offset,
                                        pair_token, pair_expert, pair_score, token_pos);

  // shared gate+up -> hs [T x DS]
  gateup_kernel<<<dim3(DS / 64, T / 128), 256, 0, stream>>>(
      xb, WsgT, WsuT, hs, DS, H, nullptr, nullptr, 0);
  // routed gate+up -> hr [PAIR_CAP x D] (A gathered by pair_token)
  gateup_kernel<<<dim3(D / 64, MT_ROUTED), 256, 0, stream>>>(
      xb, WgT, WuT, hr, D, H, pair_token, pair_expert, (long)D * H);
  // routed down -> rout [PAIR_CAP x H], scaled by pair score
  down_routed_kernel<<<dim3(H / 128, MT_ROUTED), 256, 0, stream>>>(
      hr, WdT, rout, pair_score, pair_expert);
  // shared down + combine -> out [T x H] fp32
  down_shared_kernel<<<dim3(H / 128, T / 128), 256, 0, stream>>>(
      hs, WsdT, rout, token_pos, out);
}

// Round 3
// 352.489 us; speedup vs baseline: 1.8378x; 1.0990x over previous
//
#include <hip/hip_runtime.h>

// MoE forward: shared SwiGLU expert + top-2/8 routed SwiGLU experts + aux loss.
// bf16 MFMA (16x16x32) GEMMs, 128-tile, global_load_lds width-16 staging.
// R1: atomic-free routing. R2: XOR chunk swizzle kills 16-way LDS bank
// conflicts (row stride 128B == full bank rotation); convert fused into
// router; transpose launches merged.

typedef unsigned short u16;
typedef unsigned int   u32;
typedef short short8 __attribute__((ext_vector_type(8)));
typedef float f32x4  __attribute__((ext_vector_type(4)));

#define AS1 __attribute__((address_space(1)))
#define AS3 __attribute__((address_space(3)))

constexpr int T  = 8192;
constexpr int H  = 1024;
constexpr int E  = 8;
constexpr int D  = 512;
constexpr int DS = 1024;          // shared expert width
constexpr int PAIR_CAP  = 17408;  // 136 * 128 >= 16384 + 8*127
constexpr int MT_ROUTED = 136;    // routed m-tiles (128 rows each)
constexpr int RB = 256;           // router blocks (32 tokens each)

__device__ __forceinline__ u16 f2bf(float f){
  u32 u = __builtin_bit_cast(u32, f);
  u += 0x7fffu + ((u >> 16) & 1u);   // round-to-nearest-even
  return (u16)(u >> 16);
}
__device__ __forceinline__ float bf2f(u16 h){
  u32 u = ((u32)h) << 16;
  return __builtin_bit_cast(float, u);
}

// async global->LDS, 16B per lane. LDS dest = wave-uniform base + lane*16.
__device__ __forceinline__ void gl_lds16(const u16* g, u16* l){
  __builtin_amdgcn_global_load_lds((const AS1 void*)g, (AS3 void*)l, 16, 0, 0);
}

// Stage a ROWS x 64(bf16) tile into LDS, XOR-swizzled: LDS slot (row, ch)
// holds global chunk (ch ^ (row&7)). Chunk = 16B = 8 bf16. The swizzle is
// applied on the per-lane GLOBAL source address (LDS dest must stay
// lane-ordered for global_load_lds).
template<int ROWS>
__device__ __forceinline__ void stage_tile(const u16* __restrict__ gbase, int ld, int k0,
                                           int rowbase, const int* __restrict__ gather,
                                           u16* lds, int wave, int lane){
  constexpr int ISS = ROWS / 32;   // issues per wave (4 waves total)
  int lr = lane >> 3, ch = lane & 7;
  int chs = (ch ^ lr) * 8;         // swizzled source chunk offset (elems)
#pragma unroll
  for (int j = 0; j < ISS; ++j){
    int idx = wave * ISS + j;
    int row = idx * 8 + lr;
    int grow = gather ? gather[rowbase + row] : (rowbase + row);
    const u16* g = gbase + (long)grow * ld + k0 + chs;
    gl_lds16(g, lds + idx * 512);  // 512 u16 = 1024B per issue, wave-uniform
  }
}

// Fragment read offset (elems) for logical chunk c at a row with row&7==lane&7.
__device__ __forceinline__ int swz_off(int c, int lane){
  return ((c ^ (lane & 7)) * 8);
}

// ---------------- router: logits -> softmax -> top2 + bf16 convert of x -----
// 256 blocks x 4 waves x 8 tokens. No global atomics. Also writes xb (bf16).
__global__ void __launch_bounds__(256) router_kernel(
    const float* __restrict__ x, const float* __restrict__ Wr,
    u16* __restrict__ xb,
    int* __restrict__ topk_idx, float* __restrict__ topk_w,
    int* __restrict__ partial_hist, float* __restrict__ partial_probs)
{
  __shared__ int   hist_s[4][8];
  __shared__ float ps_s[4][8];
  int tid = threadIdx.x, lane = tid & 63, wv = tid >> 6;
  int   histl[8] = {0,0,0,0,0,0,0,0};
  float psl[8]   = {0.f,0.f,0.f,0.f,0.f,0.f,0.f,0.f};

  for (int it = 0; it < 8; ++it){
    int t = blockIdx.x * 32 + wv * 8 + it;
    const float4* xr = (const float4*)(x + (long)t * H);
    uint2* xbr = (uint2*)(xb + (long)t * H);
    float acc[8];
#pragma unroll
    for (int e = 0; e < 8; ++e) acc[e] = 0.f;
#pragma unroll
    for (int i = 0; i < 4; ++i){
      float4 xv = xr[i * 64 + lane];
      u32 lo = (u32)f2bf(xv.x) | ((u32)f2bf(xv.y) << 16);
      u32 hi = (u32)f2bf(xv.z) | ((u32)f2bf(xv.w) << 16);
      xbr[i * 64 + lane] = make_uint2(lo, hi);
      int h0 = i * 256 + lane * 4;
#pragma unroll
      for (int j = 0; j < 4; ++j){
        float xs = (j == 0) ? xv.x : (j == 1) ? xv.y : (j == 2) ? xv.z : xv.w;
        const float4* wr = (const float4*)(Wr + (long)(h0 + j) * E);
        float4 w0 = wr[0], w1 = wr[1];
        acc[0] += xs * w0.x; acc[1] += xs * w0.y; acc[2] += xs * w0.z; acc[3] += xs * w0.w;
        acc[4] += xs * w1.x; acc[5] += xs * w1.y; acc[6] += xs * w1.z; acc[7] += xs * w1.w;
      }
    }
#pragma unroll
    for (int off = 32; off >= 1; off >>= 1){
#pragma unroll
      for (int e = 0; e < 8; ++e) acc[e] += __shfl_xor(acc[e], off, 64);
    }
    if (lane == 0){
      float m = acc[0];
#pragma unroll
      for (int e = 1; e < 8; ++e) m = fmaxf(m, acc[e]);
      float p[8], s = 0.f;
#pragma unroll
      for (int e = 0; e < 8; ++e){ p[e] = __expf(acc[e] - m); s += p[e]; }
      float inv = 1.f / s;
#pragma unroll
      for (int e = 0; e < 8; ++e) psl[e] += p[e] * inv;
      int i1 = 0; float v1 = p[0];
#pragma unroll
      for (int e = 1; e < 8; ++e) if (p[e] > v1){ v1 = p[e]; i1 = e; }
      int i2 = -1; float v2 = -1.f;
#pragma unroll
      for (int e = 0; e < 8; ++e) if (e != i1 && p[e] > v2){ v2 = p[e]; i2 = e; }
      float rs = 1.f / (v1 + v2);
      topk_idx[2 * t] = i1; topk_idx[2 * t + 1] = i2;
      topk_w[2 * t] = v1 * rs; topk_w[2 * t + 1] = v2 * rs;
      histl[i1]++; histl[i2]++;
    }
  }
  if (lane == 0){
#pragma unroll
    for (int e = 0; e < 8; ++e){ hist_s[wv][e] = histl[e]; ps_s[wv][e] = psl[e]; }
  }
  __syncthreads();
  if (tid < 8){
    int hs = 0; float ps = 0.f;
#pragma unroll
    for (int w = 0; w < 4; ++w){ hs += hist_s[w][tid]; ps += ps_s[w][tid]; }
    partial_hist[blockIdx.x * 8 + tid]  = hs;
    partial_probs[blockIdx.x * 8 + tid] = ps;
  }
}

// ---------------- scan: padded bases + per-block offsets + aux loss ----------
__global__ void __launch_bounds__(64) scan_kernel(
    const int* __restrict__ partial_hist, const float* __restrict__ partial_probs,
    int* __restrict__ block_offset, float* __restrict__ out_aux)
{
  __shared__ int   csum[8][8];     // [chunk][expert], chunk = 32 blocks
  __shared__ float cps[8][8];
  __shared__ int   cbase[8][8];
  __shared__ int   base_s[8];
  int tid = threadIdx.x, e = tid & 7, c = tid >> 3;
  int s = 0; float f = 0.f;
  for (int b = c * 32; b < c * 32 + 32; ++b){
    s += partial_hist[b * 8 + e]; f += partial_probs[b * 8 + e];
  }
  csum[c][e] = s; cps[c][e] = f;
  __syncthreads();
  if (tid < 8){
    int tot = 0;
    for (int cc = 0; cc < 8; ++cc){ cbase[cc][tid] = tot; tot += csum[cc][tid]; }
    csum[0][tid] = tot;            // column total (cbase already captured)
  }
  __syncthreads();
  if (tid == 0){
    int off = 0;
    for (int ee = 0; ee < 8; ++ee){ base_s[ee] = off; off += (csum[0][ee] + 127) & ~127; }
    float a = 0.f;
    for (int ee = 0; ee < 8; ++ee){
      float ps = 0.f;
      for (int cc = 0; cc < 8; ++cc) ps += cps[cc][ee];
      float m = ps * (1.f / (float)T);
      a += m * m;
    }
    out_aux[0] = (float)E * a;
  }
  __syncthreads();
  int run = base_s[e] + cbase[c][e];
  for (int b = c * 32; b < c * 32 + 32; ++b){
    block_offset[b * 8 + e] = run;
    run += partial_hist[b * 8 + e];
  }
}

// ---------------- scatter: ballot-ranked, atomic-free ------------------------
__global__ void __launch_bounds__(64) scatter_kernel(
    const int* __restrict__ topk_idx, const float* __restrict__ topk_w,
    const int* __restrict__ block_offset,
    int* __restrict__ pair_token, int* __restrict__ pair_expert,
    float* __restrict__ pair_score, int* __restrict__ token_pos)
{
  int lane = threadIdx.x, b = blockIdx.x;
  int idx = b * 64 + lane;
  int t = idx >> 1;
  int e = topk_idx[idx];
  float w = topk_w[idx];
  unsigned long long below = lane ? ((1ull << lane) - 1ull) : 0ull;
  int rank = 0, basee = 0;
#pragma unroll
  for (int ee = 0; ee < 8; ++ee){
    unsigned long long m = __ballot(e == ee);
    if (e == ee){ rank = __popcll(m & below); basee = block_offset[b * 8 + ee]; }
  }
  int pos = basee + rank;
  pair_token[pos] = t;
  pair_expert[pos] = e;
  pair_score[pos] = w;
  token_pos[idx] = pos;
}

// ---------------- transposes: [R][C] f32 -> [C][R] bf16 ----------------------
__device__ __forceinline__ void transpose_body(const float* src, u16* dst, int R, int C,
                                               int bz){
  __shared__ float tile[32][33];
  long zoff = (long)bz * R * C;
  int tx = threadIdx.x & 31, ty = threadIdx.x >> 5;
  int c = blockIdx.x * 32 + tx;
  int rb = blockIdx.y * 32;
#pragma unroll
  for (int j = 0; j < 4; ++j)
    tile[ty + j * 8][tx] = src[zoff + (long)(rb + ty + j * 8) * C + c];
  __syncthreads();
#pragma unroll
  for (int j = 0; j < 4; ++j){
    int cc = blockIdx.x * 32 + ty + j * 8;
    dst[zoff + (long)cc * R + rb + tx] = f2bf(tile[tx][ty + j * 8]);
  }
}

__global__ void __launch_bounds__(256) transpose_kernel(const float* __restrict__ src,
                                                        u16* __restrict__ dst, int R, int C){
  transpose_body(src, dst, R, C, blockIdx.z);
}

// z in [0, 2Z): first Z from s0, rest from s1 (same R, C)
__global__ void __launch_bounds__(256) transpose2_kernel(
    const float* __restrict__ s0, u16* __restrict__ d0,
    const float* __restrict__ s1, u16* __restrict__ d1, int R, int C, int Z){
  int z = blockIdx.z;
  if (z < Z) transpose_body(s0, d0, R, C, z);
  else       transpose_body(s1, d1, R, C, z - Z);
}

// three 1024x1024 single matrices (shared expert weights)
__global__ void __launch_bounds__(256) transpose3_kernel(
    const float* __restrict__ s0, u16* __restrict__ d0,
    const float* __restrict__ s1, u16* __restrict__ d1,
    const float* __restrict__ s2, u16* __restrict__ d2, int R, int C){
  int z = blockIdx.z;
  const float* s = (z == 0) ? s0 : (z == 1) ? s1 : s2;
  u16* d = (z == 0) ? d0 : (z == 1) ? d1 : d2;
  transpose_body(s, d, R, C, 0);
}

// ---------------- fused gate+up GEMM with SwiGLU epilogue --------------------
// BM=128, BN=64, BK=64. 4 waves in 2x2; wave tile 64x32.
__global__ void __launch_bounds__(256) gateup_kernel(
    const u16* __restrict__ A, const u16* __restrict__ Bg, const u16* __restrict__ Bu,
    u16* __restrict__ Hout, int N, int K,
    const int* __restrict__ gather, const int* __restrict__ pexp, long bstride)
{
  __shared__ u16 As[128 * 64];
  __shared__ u16 Bgs[64 * 64];
  __shared__ u16 Bus[64 * 64];
  int tid = threadIdx.x, lane = tid & 63, wave = tid >> 6;
  int wy = wave >> 1, wx = wave & 1;
  int m0 = blockIdx.y * 128, n0 = blockIdx.x * 64;
  int e = pexp ? pexp[m0] : 0;
  const u16* bg = Bg + (long)e * bstride;
  const u16* bu = Bu + (long)e * bstride;
  int rl = lane & 15, q = lane >> 4;

  f32x4 accG[4][2], accU[4][2];
#pragma unroll
  for (int i = 0; i < 4; ++i)
#pragma unroll
    for (int j = 0; j < 2; ++j)
#pragma unroll
      for (int r = 0; r < 4; ++r){ accG[i][j][r] = 0.f; accU[i][j][r] = 0.f; }

  for (int k0 = 0; k0 < K; k0 += 64){
    stage_tile<128>(A, K, k0, m0, gather, As, wave, lane);
    stage_tile<64>(bg, K, k0, n0, nullptr, Bgs, wave, lane);
    stage_tile<64>(bu, K, k0, n0, nullptr, Bus, wave, lane);
    __syncthreads();
#pragma unroll
    for (int ks = 0; ks < 2; ++ks){
      int off = swz_off(ks * 4 + q, lane);
      short8 a[4], g2[2], u2[2];
#pragma unroll
      for (int mt = 0; mt < 4; ++mt)
        a[mt] = *(const short8*)(As + (wy * 64 + mt * 16 + rl) * 64 + off);
#pragma unroll
      for (int nt = 0; nt < 2; ++nt){
        g2[nt] = *(const short8*)(Bgs + (wx * 32 + nt * 16 + rl) * 64 + off);
        u2[nt] = *(const short8*)(Bus + (wx * 32 + nt * 16 + rl) * 64 + off);
      }
#pragma unroll
      for (int mt = 0; mt < 4; ++mt)
#pragma unroll
        for (int nt = 0; nt < 2; ++nt){
          accG[mt][nt] = __builtin_amdgcn_mfma_f32_16x16x32_bf16(a[mt], g2[nt], accG[mt][nt], 0, 0, 0);
          accU[mt][nt] = __builtin_amdgcn_mfma_f32_16x16x32_bf16(a[mt], u2[nt], accU[mt][nt], 0, 0, 0);
        }
    }
    __syncthreads();
  }
  int row0 = m0 + wy * 64, col0 = n0 + wx * 32;
#pragma unroll
  for (int mt = 0; mt < 4; ++mt)
#pragma unroll
    for (int nt = 0; nt < 2; ++nt)
#pragma unroll
      for (int r = 0; r < 4; ++r){
        int row = row0 + mt * 16 + q * 4 + r;
        int col = col0 + nt * 16 + rl;
        float g = accG[mt][nt][r], u = accU[mt][nt][r];
        float h = g / (1.f + __expf(-g)) * u;
        Hout[(long)row * N + col] = f2bf(h);
      }
}

// ---------------- routed down GEMM: rout[pair] = score * (hr @ WdT[e]) -------
__global__ void __launch_bounds__(256) down_routed_kernel(
    const u16* __restrict__ A, const u16* __restrict__ B, u16* __restrict__ rout,
    const float* __restrict__ pair_score, const int* __restrict__ pexp)
{
  __shared__ u16 As[128 * 64];
  __shared__ u16 Bs[128 * 64];
  int tid = threadIdx.x, lane = tid & 63, wave = tid >> 6;
  int wy = wave >> 1, wx = wave & 1;
  int m0 = blockIdx.y * 128, n0 = blockIdx.x * 128;
  int e = pexp[m0];
  const u16* b = B + (long)e * (H * D);
  int rl = lane & 15, q = lane >> 4;

  f32x4 acc[4][4];
#pragma unroll
  for (int i = 0; i < 4; ++i)
#pragma unroll
    for (int j = 0; j < 4; ++j)
#pragma unroll
      for (int r = 0; r < 4; ++r) acc[i][j][r] = 0.f;

  for (int k0 = 0; k0 < D; k0 += 64){
    stage_tile<128>(A, D, k0, m0, nullptr, As, wave, lane);
    stage_tile<128>(b, D, k0, n0, nullptr, Bs, wave, lane);
    __syncthreads();
#pragma unroll
    for (int ks = 0; ks < 2; ++ks){
      int off = swz_off(ks * 4 + q, lane);
      short8 a[4], bv[4];
#pragma unroll
      for (int mt = 0; mt < 4; ++mt)
        a[mt] = *(const short8*)(As + (wy * 64 + mt * 16 + rl) * 64 + off);
#pragma unroll
      for (int nt = 0; nt < 4; ++nt)
        bv[nt] = *(const short8*)(Bs + (wx * 64 + nt * 16 + rl) * 64 + off);
#pragma unroll
      for (int mt = 0; mt < 4; ++mt)
#pragma unroll
        for (int nt = 0; nt < 4; ++nt)
          acc[mt][nt] = __builtin_amdgcn_mfma_f32_16x16x32_bf16(a[mt], bv[nt], acc[mt][nt], 0, 0, 0);
    }
    __syncthreads();
  }
#pragma unroll
  for (int mt = 0; mt < 4; ++mt)
#pragma unroll
    for (int r = 0; r < 4; ++r){
      int row = m0 + wy * 64 + mt * 16 + q * 4 + r;
      float s = pair_score[row];
      long rbase = (long)row * H;
#pragma unroll
      for (int nt = 0; nt < 4; ++nt){
        int col = n0 + wx * 64 + nt * 16 + rl;
        rout[rbase + col] = f2bf(s * acc[mt][nt][r]);
      }
    }
}

// ---------------- shared down GEMM + combine ---------------------------------
__global__ void __launch_bounds__(256) down_shared_kernel(
    const u16* __restrict__ A, const u16* __restrict__ B,
    const u16* __restrict__ rout, const int* __restrict__ token_pos,
    float* __restrict__ out)
{
  __shared__ u16 As[128 * 64];
  __shared__ u16 Bs[128 * 64];
  int tid = threadIdx.x, lane = tid & 63, wave = tid >> 6;
  int wy = wave >> 1, wx = wave & 1;
  int m0 = blockIdx.y * 128, n0 = blockIdx.x * 128;
  int rl = lane & 15, q = lane >> 4;

  f32x4 acc[4][4];
#pragma unroll
  for (int i = 0; i < 4; ++i)
#pragma unroll
    for (int j = 0; j < 4; ++j)
#pragma unroll
      for (int r = 0; r < 4; ++r) acc[i][j][r] = 0.f;

  for (int k0 = 0; k0 < DS; k0 += 64){
    stage_tile<128>(A, DS, k0, m0, nullptr, As, wave, lane);
    stage_tile<128>(B, DS, k0, n0, nullptr, Bs, wave, lane);
    __syncthreads();
#pragma unroll
    for (int ks = 0; ks < 2; ++ks){
      int off = swz_off(ks * 4 + q, lane);
      short8 a[4], bv[4];
#pragma unroll
      for (int mt = 0; mt < 4; ++mt)
        a[mt] = *(const short8*)(As + (wy * 64 + mt * 16 + rl) * 64 + off);
#pragma unroll
      for (int nt = 0; nt < 4; ++nt)
        bv[nt] = *(const short8*)(Bs + (wx * 64 + nt * 16 + rl) * 64 + off);
#pragma unroll
      for (int mt = 0; mt < 4; ++mt)
#pragma unroll
        for (int nt = 0; nt < 4; ++nt)
          acc[mt][nt] = __builtin_amdgcn_mfma_f32_16x16x32_bf16(a[mt], bv[nt], acc[mt][nt], 0, 0, 0);
    }
    __syncthreads();
  }
#pragma unroll
  for (int mt = 0; mt < 4; ++mt)
#pragma unroll
    for (int r = 0; r < 4; ++r){
      int row = m0 + wy * 64 + mt * 16 + q * 4 + r;
      int p0 = token_pos[2 * row], p1 = token_pos[2 * row + 1];
      long o = (long)row * H;
#pragma unroll
      for (int nt = 0; nt < 4; ++nt){
        int col = n0 + wx * 64 + nt * 16 + rl;
        out[o + col] = acc[mt][nt][r]
                     + bf2f(rout[(long)p0 * H + col])
                     + bf2f(rout[(long)p1 * H + col]);
      }
    }
}

// ---------------- launch -----------------------------------------------------
extern "C" void kernel_launch(void* const* d_in, const int* in_sizes, int n_in,
                              void* d_out, int out_size, void* d_ws, size_t ws_size,
                              hipStream_t stream)
{
  (void)in_sizes; (void)n_in; (void)out_size; (void)ws_size;
  const float* x   = (const float*)d_in[0];
  const float* Wr  = (const float*)d_in[1];
  const float* Wg  = (const float*)d_in[2];
  const float* Wu  = (const float*)d_in[3];
  const float* Wd  = (const float*)d_in[4];
  const float* Wsg = (const float*)d_in[5];
  const float* Wsu = (const float*)d_in[6];
  const float* Wsd = (const float*)d_in[7];
  float* out = (float*)d_out;

  char* ws = (char*)d_ws;
  size_t off = 0;
  auto alloc = [&](size_t bytes) -> void* {
    void* p = ws + off; off += (bytes + 255) & ~(size_t)255; return p;
  };
  u16* xb   = (u16*)alloc((size_t)T * H * 2);
  u16* WsgT = (u16*)alloc((size_t)DS * H * 2);
  u16* WsuT = (u16*)alloc((size_t)DS * H * 2);
  u16* WsdT = (u16*)alloc((size_t)H * DS * 2);
  u16* WgT  = (u16*)alloc((size_t)E * D * H * 2);
  u16* WuT  = (u16*)alloc((size_t)E * D * H * 2);
  u16* WdT  = (u16*)alloc((size_t)E * H * D * 2);
  u16* hs   = (u16*)alloc((size_t)T * DS * 2);
  u16* hr   = (u16*)alloc((size_t)PAIR_CAP * D * 2);
  u16* rout = (u16*)alloc((size_t)PAIR_CAP * H * 2);
  int*   topk_idx  = (int*)alloc((size_t)T * 2 * 4);
  float* topk_w    = (float*)alloc((size_t)T * 2 * 4);
  int*   token_pos = (int*)alloc((size_t)T * 2 * 4);
  int*   partial_hist  = (int*)alloc((size_t)RB * 8 * 4);
  float* partial_probs = (float*)alloc((size_t)RB * 8 * 4);
  int*   block_offset  = (int*)alloc((size_t)RB * 8 * 4);
  // zero-initialized region (dummy pair slots must read as 0)
  char* zbase = ws + off;
  int*   pair_token  = (int*)alloc((size_t)PAIR_CAP * 4);
  int*   pair_expert = (int*)alloc((size_t)PAIR_CAP * 4);
  float* pair_score  = (float*)alloc((size_t)PAIR_CAP * 4);
  size_t zbytes = (size_t)((ws + off) - zbase);

  hipMemsetAsync(zbase, 0, zbytes, stream);

  // weight transposes (3 launches)
  transpose3_kernel<<<dim3(32, 32, 3), 256, 0, stream>>>(
      Wsg, WsgT, Wsu, WsuT, Wsd, WsdT, 1024, 1024);
  transpose2_kernel<<<dim3(D / 32, H / 32, 2 * E), 256, 0, stream>>>(
      Wg, WgT, Wu, WuT, H, D, E);
  transpose_kernel<<<dim3(H / 32, D / 32, E), 256, 0, stream>>>(Wd, WdT, D, H);

  router_kernel<<<RB, 256, 0, stream>>>(x, Wr, xb, topk_idx, topk_w,
                                        partial_hist, partial_probs);
  scan_kernel<<<1, 64, 0, stream>>>(partial_hist, partial_probs, block_offset,
                                    out + (size_t)T * H);
  scatter_kernel<<<RB, 64, 0, stream>>>(topk_idx, topk_w, block_offset,
                                        pair_token, pair_expert, pair_score, token_pos);

  // shared gate+up -> hs [T x DS]
  gateup_kernel<<<dim3(DS / 64, T / 128), 256, 0, stream>>>(
      xb, WsgT, WsuT, hs, DS, H, nullptr, nullptr, 0);
  // routed gate+up -> hr [PAIR_CAP x D] (A gathered by pair_token)
  gateup_kernel<<<dim3(D / 64, MT_ROUTED), 256, 0, stream>>>(
      xb, WgT, WuT, hr, D, H, pair_token, pair_expert, (long)D * H);
  // routed down -> rout [PAIR_CAP x H], scaled by pair score
  down_routed_kernel<<<dim3(H / 128, MT_ROUTED), 256, 0, stream>>>(
      hr, WdT, rout, pair_score, pair_expert);
  // shared down + combine -> out [T x H] fp32
  down_shared_kernel<<<dim3(H / 128, T / 128), 256, 0, stream>>>(
      hs, WsdT, rout, token_pos, out);
}

// Round 4
// 329.934 us; speedup vs baseline: 1.9634x; 1.0684x over previous
//
#include <hip/hip_runtime.h>

// MoE forward: shared SwiGLU expert + top-2/8 routed SwiGLU experts + aux loss.
// bf16 MFMA (16x16x32) GEMMs, 128-tile, global_load_lds width-16 staging.
// R1: atomic-free routing. R2: XOR chunk swizzle (0 LDS bank conflicts).
// R3: double-buffered LDS with raw s_barrier + precise vmcnt(8) (no full
// vmcnt(0) drain per K-iter) + XCD-aware block swizzle for L2 locality.

typedef unsigned short u16;
typedef unsigned int   u32;
typedef short short8 __attribute__((ext_vector_type(8)));
typedef float f32x4  __attribute__((ext_vector_type(4)));

#define AS1 __attribute__((address_space(1)))
#define AS3 __attribute__((address_space(3)))

constexpr int T  = 8192;
constexpr int H  = 1024;
constexpr int E  = 8;
constexpr int D  = 512;
constexpr int DS = 1024;          // shared expert width
constexpr int PAIR_CAP  = 17408;  // 136 * 128 >= 16384 + 8*127
constexpr int MT_ROUTED = 136;    // routed m-tiles (128 rows each)
constexpr int RB = 256;           // router blocks (32 tokens each)

__device__ __forceinline__ u16 f2bf(float f){
  u32 u = __builtin_bit_cast(u32, f);
  u += 0x7fffu + ((u >> 16) & 1u);   // round-to-nearest-even
  return (u16)(u >> 16);
}
__device__ __forceinline__ float bf2f(u16 h){
  u32 u = ((u32)h) << 16;
  return __builtin_bit_cast(float, u);
}

// async global->LDS, 16B per lane. LDS dest = wave-uniform base + lane*16.
__device__ __forceinline__ void gl_lds16(const u16* g, u16* l){
  __builtin_amdgcn_global_load_lds((const AS1 void*)g, (AS3 void*)l, 16, 0, 0);
}

// s_waitcnt with expcnt/lgkmcnt wildcarded: imm = vm[3:0] | 0x70 | 0xf00 | vm[5:4]<<14
__device__ __forceinline__ void wait_vmcnt8(){ __builtin_amdgcn_s_waitcnt(0x0f78); }
__device__ __forceinline__ void wait_vmcnt0(){ __builtin_amdgcn_s_waitcnt(0x0f70); }

// workgroup barrier with LDS-only ordering (no global vmcnt drain)
__device__ __forceinline__ void bar_sync(){
  __builtin_amdgcn_fence(__ATOMIC_RELEASE, "workgroup", "local");
  __builtin_amdgcn_s_barrier();
  __builtin_amdgcn_fence(__ATOMIC_ACQUIRE, "workgroup", "local");
}

// XCD-aware tile remap: all n-tiles of an m-tile go to one XCD, consecutively.
// Requires gridDim.y % 8 == 0. Assumes round-robin block->XCD dispatch (perf
// heuristic only; any mapping is correct).
__device__ __forceinline__ void xcd_remap(int& mtile, int& ntile){
  int NT = gridDim.x;
  int lid = blockIdx.y * NT + blockIdx.x;
  int x8 = lid & 7, s = lid >> 3;
  mtile = x8 + 8 * (s / NT);
  ntile = s % NT;
}

// Per-wave staging pointers for a ROWS x 64(bf16) tile, XOR-swizzled:
// LDS slot (row, ch) holds global chunk (ch ^ (row&7)); swizzle applied on the
// per-lane GLOBAL source address (LDS dest must stay lane-ordered for
// global_load_lds). Row pointers precomputed once (gather loads hoisted).
template<int ISS>
struct StagePtr { const u16* p[ISS]; };

template<int ROWS>
__device__ __forceinline__ void stage_init(StagePtr<ROWS/32>& sp,
    const u16* __restrict__ gbase, int ld, int rowbase,
    const int* __restrict__ gather, int wave, int lane){
  constexpr int ISS = ROWS / 32;
  int lr = lane >> 3, ch = lane & 7;
  int chs = (ch ^ lr) * 8;         // swizzled source chunk offset (elems)
#pragma unroll
  for (int j = 0; j < ISS; ++j){
    int idx = wave * ISS + j;
    int row = idx * 8 + lr;
    int grow = gather ? gather[rowbase + row] : (rowbase + row);
    sp.p[j] = gbase + (long)grow * ld + chs;
  }
}

template<int ROWS>
__device__ __forceinline__ void stage_issue(const StagePtr<ROWS/32>& sp, int k0,
                                            u16* lds, int wave, int lane){
  constexpr int ISS = ROWS / 32;
#pragma unroll
  for (int j = 0; j < ISS; ++j)
    gl_lds16(sp.p[j] + k0, lds + (wave * ISS + j) * 512);
}

// Fragment read offset (elems) for logical chunk c at a row with row&7==lane&7.
__device__ __forceinline__ int swz_off(int c, int lane){
  return ((c ^ (lane & 7)) * 8);
}

// ---------------- router: logits -> softmax -> top2 + bf16 convert of x -----
__global__ void __launch_bounds__(256) router_kernel(
    const float* __restrict__ x, const float* __restrict__ Wr,
    u16* __restrict__ xb,
    int* __restrict__ topk_idx, float* __restrict__ topk_w,
    int* __restrict__ partial_hist, float* __restrict__ partial_probs)
{
  __shared__ int   hist_s[4][8];
  __shared__ float ps_s[4][8];
  int tid = threadIdx.x, lane = tid & 63, wv = tid >> 6;
  int   histl[8] = {0,0,0,0,0,0,0,0};
  float psl[8]   = {0.f,0.f,0.f,0.f,0.f,0.f,0.f,0.f};

  for (int it = 0; it < 8; ++it){
    int t = blockIdx.x * 32 + wv * 8 + it;
    const float4* xr = (const float4*)(x + (long)t * H);
    uint2* xbr = (uint2*)(xb + (long)t * H);
    float acc[8];
#pragma unroll
    for (int e = 0; e < 8; ++e) acc[e] = 0.f;
#pragma unroll
    for (int i = 0; i < 4; ++i){
      float4 xv = xr[i * 64 + lane];
      u32 lo = (u32)f2bf(xv.x) | ((u32)f2bf(xv.y) << 16);
      u32 hi = (u32)f2bf(xv.z) | ((u32)f2bf(xv.w) << 16);
      xbr[i * 64 + lane] = make_uint2(lo, hi);
      int h0 = i * 256 + lane * 4;
#pragma unroll
      for (int j = 0; j < 4; ++j){
        float xs = (j == 0) ? xv.x : (j == 1) ? xv.y : (j == 2) ? xv.z : xv.w;
        const float4* wr = (const float4*)(Wr + (long)(h0 + j) * E);
        float4 w0 = wr[0], w1 = wr[1];
        acc[0] += xs * w0.x; acc[1] += xs * w0.y; acc[2] += xs * w0.z; acc[3] += xs * w0.w;
        acc[4] += xs * w1.x; acc[5] += xs * w1.y; acc[6] += xs * w1.z; acc[7] += xs * w1.w;
      }
    }
#pragma unroll
    for (int off = 32; off >= 1; off >>= 1){
#pragma unroll
      for (int e = 0; e < 8; ++e) acc[e] += __shfl_xor(acc[e], off, 64);
    }
    if (lane == 0){
      float m = acc[0];
#pragma unroll
      for (int e = 1; e < 8; ++e) m = fmaxf(m, acc[e]);
      float p[8], s = 0.f;
#pragma unroll
      for (int e = 0; e < 8; ++e){ p[e] = __expf(acc[e] - m); s += p[e]; }
      float inv = 1.f / s;
#pragma unroll
      for (int e = 0; e < 8; ++e) psl[e] += p[e] * inv;
      int i1 = 0; float v1 = p[0];
#pragma unroll
      for (int e = 1; e < 8; ++e) if (p[e] > v1){ v1 = p[e]; i1 = e; }
      int i2 = -1; float v2 = -1.f;
#pragma unroll
      for (int e = 0; e < 8; ++e) if (e != i1 && p[e] > v2){ v2 = p[e]; i2 = e; }
      float rs = 1.f / (v1 + v2);
      topk_idx[2 * t] = i1; topk_idx[2 * t + 1] = i2;
      topk_w[2 * t] = v1 * rs; topk_w[2 * t + 1] = v2 * rs;
      histl[i1]++; histl[i2]++;
    }
  }
  if (lane == 0){
#pragma unroll
    for (int e = 0; e < 8; ++e){ hist_s[wv][e] = histl[e]; ps_s[wv][e] = psl[e]; }
  }
  __syncthreads();
  if (tid < 8){
    int hs = 0; float ps = 0.f;
#pragma unroll
    for (int w = 0; w < 4; ++w){ hs += hist_s[w][tid]; ps += ps_s[w][tid]; }
    partial_hist[blockIdx.x * 8 + tid]  = hs;
    partial_probs[blockIdx.x * 8 + tid] = ps;
  }
}

// ---------------- scan: padded bases + per-block offsets + aux loss ----------
__global__ void __launch_bounds__(64) scan_kernel(
    const int* __restrict__ partial_hist, const float* __restrict__ partial_probs,
    int* __restrict__ block_offset, float* __restrict__ out_aux)
{
  __shared__ int   csum[8][8];     // [chunk][expert], chunk = 32 blocks
  __shared__ float cps[8][8];
  __shared__ int   cbase[8][8];
  __shared__ int   base_s[8];
  int tid = threadIdx.x, e = tid & 7, c = tid >> 3;
  int s = 0; float f = 0.f;
  for (int b = c * 32; b < c * 32 + 32; ++b){
    s += partial_hist[b * 8 + e]; f += partial_probs[b * 8 + e];
  }
  csum[c][e] = s; cps[c][e] = f;
  __syncthreads();
  if (tid < 8){
    int tot = 0;
    for (int cc = 0; cc < 8; ++cc){ cbase[cc][tid] = tot; tot += csum[cc][tid]; }
    csum[0][tid] = tot;            // column total (cbase already captured)
  }
  __syncthreads();
  if (tid == 0){
    int off = 0;
    for (int ee = 0; ee < 8; ++ee){ base_s[ee] = off; off += (csum[0][ee] + 127) & ~127; }
    float a = 0.f;
    for (int ee = 0; ee < 8; ++ee){
      float ps = 0.f;
      for (int cc = 0; cc < 8; ++cc) ps += cps[cc][ee];
      float m = ps * (1.f / (float)T);
      a += m * m;
    }
    out_aux[0] = (float)E * a;
  }
  __syncthreads();
  int run = base_s[e] + cbase[c][e];
  for (int b = c * 32; b < c * 32 + 32; ++b){
    block_offset[b * 8 + e] = run;
    run += partial_hist[b * 8 + e];
  }
}

// ---------------- scatter: ballot-ranked, atomic-free ------------------------
__global__ void __launch_bounds__(64) scatter_kernel(
    const int* __restrict__ topk_idx, const float* __restrict__ topk_w,
    const int* __restrict__ block_offset,
    int* __restrict__ pair_token, int* __restrict__ pair_expert,
    float* __restrict__ pair_score, int* __restrict__ token_pos)
{
  int lane = threadIdx.x, b = blockIdx.x;
  int idx = b * 64 + lane;
  int t = idx >> 1;
  int e = topk_idx[idx];
  float w = topk_w[idx];
  unsigned long long below = lane ? ((1ull << lane) - 1ull) : 0ull;
  int rank = 0, basee = 0;
#pragma unroll
  for (int ee = 0; ee < 8; ++ee){
    unsigned long long m = __ballot(e == ee);
    if (e == ee){ rank = __popcll(m & below); basee = block_offset[b * 8 + ee]; }
  }
  int pos = basee + rank;
  pair_token[pos] = t;
  pair_expert[pos] = e;
  pair_score[pos] = w;
  token_pos[idx] = pos;
}

// ---------------- transposes: [R][C] f32 -> [C][R] bf16 ----------------------
__device__ __forceinline__ void transpose_body(const float* src, u16* dst, int R, int C,
                                               int bz){
  __shared__ float tile[32][33];
  long zoff = (long)bz * R * C;
  int tx = threadIdx.x & 31, ty = threadIdx.x >> 5;
  int c = blockIdx.x * 32 + tx;
  int rb = blockIdx.y * 32;
#pragma unroll
  for (int j = 0; j < 4; ++j)
    tile[ty + j * 8][tx] = src[zoff + (long)(rb + ty + j * 8) * C + c];
  __syncthreads();
#pragma unroll
  for (int j = 0; j < 4; ++j){
    int cc = blockIdx.x * 32 + ty + j * 8;
    dst[zoff + (long)cc * R + rb + tx] = f2bf(tile[tx][ty + j * 8]);
  }
}

__global__ void __launch_bounds__(256) transpose_kernel(const float* __restrict__ src,
                                                        u16* __restrict__ dst, int R, int C){
  transpose_body(src, dst, R, C, blockIdx.z);
}

__global__ void __launch_bounds__(256) transpose2_kernel(
    const float* __restrict__ s0, u16* __restrict__ d0,
    const float* __restrict__ s1, u16* __restrict__ d1, int R, int C, int Z){
  int z = blockIdx.z;
  if (z < Z) transpose_body(s0, d0, R, C, z);
  else       transpose_body(s1, d1, R, C, z - Z);
}

__global__ void __launch_bounds__(256) transpose3_kernel(
    const float* __restrict__ s0, u16* __restrict__ d0,
    const float* __restrict__ s1, u16* __restrict__ d1,
    const float* __restrict__ s2, u16* __restrict__ d2, int R, int C){
  int z = blockIdx.z;
  const float* s = (z == 0) ? s0 : (z == 1) ? s1 : s2;
  u16* d = (z == 0) ? d0 : (z == 1) ? d1 : d2;
  transpose_body(s, d, R, C, 0);
}

// ---------------- fused gate+up GEMM with SwiGLU epilogue --------------------
// BM=128, BN=64, BK=64, double-buffered. 4 waves in 2x2; wave tile 64x32.
__global__ void __launch_bounds__(256) gateup_kernel(
    const u16* __restrict__ A, const u16* __restrict__ Bg, const u16* __restrict__ Bu,
    u16* __restrict__ Hout, int N, int K,
    const int* __restrict__ gather, const int* __restrict__ pexp, long bstride)
{
  __shared__ u16 As[2][128 * 64];
  __shared__ u16 Bgs[2][64 * 64];
  __shared__ u16 Bus[2][64 * 64];
  int tid = threadIdx.x, lane = tid & 63, wave = tid >> 6;
  int wy = wave >> 1, wx = wave & 1;
  int mtile, ntile; xcd_remap(mtile, ntile);
  int m0 = mtile * 128, n0 = ntile * 64;
  int e = pexp ? pexp[m0] : 0;
  const u16* bg = Bg + (long)e * bstride;
  const u16* bu = Bu + (long)e * bstride;
  int rl = lane & 15, q = lane >> 4;

  StagePtr<4> spA; StagePtr<2> spG; StagePtr<2> spU;
  stage_init<128>(spA, A, K, m0, gather, wave, lane);
  stage_init<64>(spG, bg, K, n0, nullptr, wave, lane);
  stage_init<64>(spU, bu, K, n0, nullptr, wave, lane);

  f32x4 accG[4][2], accU[4][2];
#pragma unroll
  for (int i = 0; i < 4; ++i)
#pragma unroll
    for (int j = 0; j < 2; ++j)
#pragma unroll
      for (int r = 0; r < 4; ++r){ accG[i][j][r] = 0.f; accU[i][j][r] = 0.f; }

  stage_issue<128>(spA, 0, As[0], wave, lane);
  stage_issue<64>(spG, 0, Bgs[0], wave, lane);
  stage_issue<64>(spU, 0, Bus[0], wave, lane);

  int NI = K / 64;
  for (int i = 0; i < NI; ++i){
    int cur = i & 1, nxt = cur ^ 1;
    if (i + 1 < NI){
      int kn = (i + 1) * 64;
      stage_issue<128>(spA, kn, As[nxt], wave, lane);
      stage_issue<64>(spG, kn, Bgs[nxt], wave, lane);
      stage_issue<64>(spU, kn, Bus[nxt], wave, lane);
      wait_vmcnt8();               // cur tiles complete; nxt (8/wave) in flight
    } else {
      wait_vmcnt0();
    }
    bar_sync();
#pragma unroll
    for (int ks = 0; ks < 2; ++ks){
      int off = swz_off(ks * 4 + q, lane);
      short8 a[4], g2[2], u2[2];
#pragma unroll
      for (int mt = 0; mt < 4; ++mt)
        a[mt] = *(const short8*)(As[cur] + (wy * 64 + mt * 16 + rl) * 64 + off);
#pragma unroll
      for (int nt = 0; nt < 2; ++nt){
        g2[nt] = *(const short8*)(Bgs[cur] + (wx * 32 + nt * 16 + rl) * 64 + off);
        u2[nt] = *(const short8*)(Bus[cur] + (wx * 32 + nt * 16 + rl) * 64 + off);
      }
#pragma unroll
      for (int mt = 0; mt < 4; ++mt)
#pragma unroll
        for (int nt = 0; nt < 2; ++nt){
          accG[mt][nt] = __builtin_amdgcn_mfma_f32_16x16x32_bf16(a[mt], g2[nt], accG[mt][nt], 0, 0, 0);
          accU[mt][nt] = __builtin_amdgcn_mfma_f32_16x16x32_bf16(a[mt], u2[nt], accU[mt][nt], 0, 0, 0);
        }
    }
    if (i + 1 < NI) bar_sync();    // all waves done reading cur before overwrite
  }
  int row0 = m0 + wy * 64, col0 = n0 + wx * 32;
#pragma unroll
  for (int mt = 0; mt < 4; ++mt)
#pragma unroll
    for (int nt = 0; nt < 2; ++nt)
#pragma unroll
      for (int r = 0; r < 4; ++r){
        int row = row0 + mt * 16 + q * 4 + r;
        int col = col0 + nt * 16 + rl;
        float g = accG[mt][nt][r], u = accU[mt][nt][r];
        float h = g / (1.f + __expf(-g)) * u;
        Hout[(long)row * N + col] = f2bf(h);
      }
}

// ---------------- down GEMM core: BM=128, BN=128, BK=64, double-buffered -----
// ROUTED: scale by pair_score, bf16 store to rout.
// SHARED: add routed rows via token_pos, fp32 store to out.
template<bool ROUTED>
__device__ __forceinline__ void down_body(
    const u16* __restrict__ A, const u16* __restrict__ Bbase, int K,
    u16* __restrict__ rout, const float* __restrict__ pair_score,
    const int* __restrict__ token_pos, float* __restrict__ out)
{
  __shared__ u16 As[2][128 * 64];
  __shared__ u16 Bs[2][128 * 64];
  int tid = threadIdx.x, lane = tid & 63, wave = tid >> 6;
  int wy = wave >> 1, wx = wave & 1;
  int mtile, ntile; xcd_remap(mtile, ntile);
  int m0 = mtile * 128, n0 = ntile * 128;
  int rl = lane & 15, q = lane >> 4;

  StagePtr<4> spA, spB;
  stage_init<128>(spA, A, K, m0, nullptr, wave, lane);
  stage_init<128>(spB, Bbase, K, n0, nullptr, wave, lane);

  f32x4 acc[4][4];
#pragma unroll
  for (int i = 0; i < 4; ++i)
#pragma unroll
    for (int j = 0; j < 4; ++j)
#pragma unroll
      for (int r = 0; r < 4; ++r) acc[i][j][r] = 0.f;

  stage_issue<128>(spA, 0, As[0], wave, lane);
  stage_issue<128>(spB, 0, Bs[0], wave, lane);

  int NI = K / 64;
  for (int i = 0; i < NI; ++i){
    int cur = i & 1, nxt = cur ^ 1;
    if (i + 1 < NI){
      int kn = (i + 1) * 64;
      stage_issue<128>(spA, kn, As[nxt], wave, lane);
      stage_issue<128>(spB, kn, Bs[nxt], wave, lane);
      wait_vmcnt8();
    } else {
      wait_vmcnt0();
    }
    bar_sync();
#pragma unroll
    for (int ks = 0; ks < 2; ++ks){
      int off = swz_off(ks * 4 + q, lane);
      short8 a[4], bv[4];
#pragma unroll
      for (int mt = 0; mt < 4; ++mt)
        a[mt] = *(const short8*)(As[cur] + (wy * 64 + mt * 16 + rl) * 64 + off);
#pragma unroll
      for (int nt = 0; nt < 4; ++nt)
        bv[nt] = *(const short8*)(Bs[cur] + (wx * 64 + nt * 16 + rl) * 64 + off);
#pragma unroll
      for (int mt = 0; mt < 4; ++mt)
#pragma unroll
        for (int nt = 0; nt < 4; ++nt)
          acc[mt][nt] = __builtin_amdgcn_mfma_f32_16x16x32_bf16(a[mt], bv[nt], acc[mt][nt], 0, 0, 0);
    }
    if (i + 1 < NI) bar_sync();
  }
#pragma unroll
  for (int mt = 0; mt < 4; ++mt)
#pragma unroll
    for (int r = 0; r < 4; ++r){
      int row = m0 + wy * 64 + mt * 16 + q * 4 + r;
      if (ROUTED){
        float s = pair_score[row];
        long rbase = (long)row * H;
#pragma unroll
        for (int nt = 0; nt < 4; ++nt){
          int col = n0 + wx * 64 + nt * 16 + rl;
          rout[rbase + col] = f2bf(s * acc[mt][nt][r]);
        }
      } else {
        int p0 = token_pos[2 * row], p1 = token_pos[2 * row + 1];
        long o = (long)row * H;
#pragma unroll
        for (int nt = 0; nt < 4; ++nt){
          int col = n0 + wx * 64 + nt * 16 + rl;
          out[o + col] = acc[mt][nt][r]
                       + bf2f(rout[(long)p0 * H + col])
                       + bf2f(rout[(long)p1 * H + col]);
        }
      }
    }
}

__global__ void __launch_bounds__(256) down_routed_kernel(
    const u16* __restrict__ A, const u16* __restrict__ B, u16* __restrict__ rout,
    const float* __restrict__ pair_score, const int* __restrict__ pexp)
{
  int NT = gridDim.x;
  int lid = blockIdx.y * NT + blockIdx.x;
  int x8 = lid & 7, s = lid >> 3;
  int mtile = x8 + 8 * (s / NT);
  int e = pexp[mtile * 128];
  down_body<true>(A, B + (long)e * (H * D), D, rout, pair_score, nullptr, nullptr);
}

__global__ void __launch_bounds__(256) down_shared_kernel(
    const u16* __restrict__ A, const u16* __restrict__ B,
    const u16* __restrict__ rout, const int* __restrict__ token_pos,
    float* __restrict__ out)
{
  down_body<false>(A, B, DS, const_cast<u16*>(rout), nullptr, token_pos, out);
}

// ---------------- launch -----------------------------------------------------
extern "C" void kernel_launch(void* const* d_in, const int* in_sizes, int n_in,
                              void* d_out, int out_size, void* d_ws, size_t ws_size,
                              hipStream_t stream)
{
  (void)in_sizes; (void)n_in; (void)out_size; (void)ws_size;
  const float* x   = (const float*)d_in[0];
  const float* Wr  = (const float*)d_in[1];
  const float* Wg  = (const float*)d_in[2];
  const float* Wu  = (const float*)d_in[3];
  const float* Wd  = (const float*)d_in[4];
  const float* Wsg = (const float*)d_in[5];
  const float* Wsu = (const float*)d_in[6];
  const float* Wsd = (const float*)d_in[7];
  float* out = (float*)d_out;

  char* ws = (char*)d_ws;
  size_t off = 0;
  auto alloc = [&](size_t bytes) -> void* {
    void* p = ws + off; off += (bytes + 255) & ~(size_t)255; return p;
  };
  u16* xb   = (u16*)alloc((size_t)T * H * 2);
  u16* WsgT = (u16*)alloc((size_t)DS * H * 2);
  u16* WsuT = (u16*)alloc((size_t)DS * H * 2);
  u16* WsdT = (u16*)alloc((size_t)H * DS * 2);
  u16* WgT  = (u16*)alloc((size_t)E * D * H * 2);
  u16* WuT  = (u16*)alloc((size_t)E * D * H * 2);
  u16* WdT  = (u16*)alloc((size_t)E * H * D * 2);
  u16* hs   = (u16*)alloc((size_t)T * DS * 2);
  u16* hr   = (u16*)alloc((size_t)PAIR_CAP * D * 2);
  u16* rout = (u16*)alloc((size_t)PAIR_CAP * H * 2);
  int*   topk_idx  = (int*)alloc((size_t)T * 2 * 4);
  float* topk_w    = (float*)alloc((size_t)T * 2 * 4);
  int*   token_pos = (int*)alloc((size_t)T * 2 * 4);
  int*   partial_hist  = (int*)alloc((size_t)RB * 8 * 4);
  float* partial_probs = (float*)alloc((size_t)RB * 8 * 4);
  int*   block_offset  = (int*)alloc((size_t)RB * 8 * 4);
  // zero-initialized region (dummy pair slots must read as 0)
  char* zbase = ws + off;
  int*   pair_token  = (int*)alloc((size_t)PAIR_CAP * 4);
  int*   pair_expert = (int*)alloc((size_t)PAIR_CAP * 4);
  float* pair_score  = (float*)alloc((size_t)PAIR_CAP * 4);
  size_t zbytes = (size_t)((ws + off) - zbase);

  hipMemsetAsync(zbase, 0, zbytes, stream);

  // weight transposes (3 launches)
  transpose3_kernel<<<dim3(32, 32, 3), 256, 0, stream>>>(
      Wsg, WsgT, Wsu, WsuT, Wsd, WsdT, 1024, 1024);
  transpose2_kernel<<<dim3(D / 32, H / 32, 2 * E), 256, 0, stream>>>(
      Wg, WgT, Wu, WuT, H, D, E);
  transpose_kernel<<<dim3(H / 32, D / 32, E), 256, 0, stream>>>(Wd, WdT, D, H);

  router_kernel<<<RB, 256, 0, stream>>>(x, Wr, xb, topk_idx, topk_w,
                                        partial_hist, partial_probs);
  scan_kernel<<<1, 64, 0, stream>>>(partial_hist, partial_probs, block_offset,
                                    out + (size_t)T * H);
  scatter_kernel<<<RB, 64, 0, stream>>>(topk_idx, topk_w, block_offset,
                                        pair_token, pair_expert, pair_score, token_pos);

  // shared gate+up -> hs [T x DS]
  gateup_kernel<<<dim3(DS / 64, T / 128), 256, 0, stream>>>(
      xb, WsgT, WsuT, hs, DS, H, nullptr, nullptr, 0);
  // routed gate+up -> hr [PAIR_CAP x D] (A gathered by pair_token)
  gateup_kernel<<<dim3(D / 64, MT_ROUTED), 256, 0, stream>>>(
      xb, WgT, WuT, hr, D, H, pair_token, pair_expert, (long)D * H);
  // routed down -> rout [PAIR_CAP x H], scaled by pair score
  down_routed_kernel<<<dim3(H / 128, MT_ROUTED), 256, 0, stream>>>(
      hr, WdT, rout, pair_score, pair_expert);
  // shared down + combine -> out [T x H] fp32
  down_shared_kernel<<<dim3(H / 128, T / 128), 256, 0, stream>>>(
      hs, WsdT, rout, token_pos, out);
}